// Round 1
// baseline (1375.715 us; speedup 1.0000x reference)
//
#include <hip/hip_runtime.h>
#include <math.h>

namespace {

constexpr int   STEPS = 100;
constexpr int   BATCH = 2048;
constexpr float DT    = 0.05f;
constexpr float DAMP  = 0.01f;
constexpr float EPSV  = 1e-8f;
constexpr int   NT    = 4;   // trajectories per wave (2 pairs)

__device__ __forceinline__ float wsum(float v) {
#pragma unroll
  for (int o = 32; o > 0; o >>= 1) v += __shfl_xor(v, o, 64);
  return v;
}

__global__ __launch_bounds__(256, 1)
void geo_scramble_kernel(const float* __restrict__ q0g, const float* __restrict__ pdg,
                         const float* __restrict__ W1g, const float* __restrict__ b1g,
                         const float* __restrict__ W2g, const float* __restrict__ b2g,
                         const float* __restrict__ W3g, float* __restrict__ out)
{
  // W1s[i][h]  : [64][130]  (stride 130 == 2 mod 32 -> both read orientations conflict-free)
  // W2Ts[j][k] : [64][130]  (W2Ts[j][k] = W2[k][j])
  __shared__ __align__(16) float W1s[64 * 130];
  __shared__ __align__(16) float W2Ts[64 * 130];
  __shared__ __align__(16) float stg_all[4][NT][128];  // per-wave broadcast staging

  const int tid  = threadIdx.x;
  const int lane = tid & 63;
  const int wave = tid >> 6;

  for (int idx = tid; idx < 64 * 128; idx += 256) {
    int r = idx >> 7, c = idx & 127;
    W1s[r * 130 + c] = W1g[idx];
  }
  for (int idx = tid; idx < 64 * 128; idx += 256) {
    int j = idx >> 7, k = idx & 127;
    W2Ts[j * 130 + k] = W2g[k * 64 + j];
  }
  __syncthreads();

  const float rb10 = b1g[2 * lane];
  const float rb11 = b1g[2 * lane + 1];
  const float rb2  = b2g[lane];
  const float rw3  = W3g[lane];

  float (*stg)[128] = stg_all[wave];
  const int pair0 = blockIdx.x * 8 + wave * 2;
  const int l2 = lane << 1;

  float q[NT], p[NT], g[NT];
#pragma unroll
  for (int t = 0; t < NT; ++t) {
    int pr = pair0 + (t >> 1);
    float base = q0g[pr * 64 + lane];
    if (t & 1) {
      float qp = base + 1e-4f * pdg[pr * 64 + lane];
      float n  = sqrtf(wsum(qp * qp));
      float sc = (n > 0.99f) ? (0.99f / (n + EPSV)) : 1.0f;
      q[t] = qp * sc;
    } else {
      q[t] = base;
    }
    p[t] = 0.0f;
  }

  // Batched gradient of V(q) = W3 . silu(W2 . silu(W1 q + b1) + b2) for NT trajectories.
  // Lane j owns latent dim j and hidden dims {2j, 2j+1}.
  auto evalgrad = [&](const float* x, float* gr) {
    // stage input for broadcast
#pragma unroll
    for (int t = 0; t < NT; ++t) stg[t][lane] = x[t];

    // ---- layer1 forward: z1 = W1^T q + b1 ----
    float a0[NT], a1[NT];
#pragma unroll
    for (int t = 0; t < NT; ++t) { a0[t] = rb10; a1[t] = rb11; }
    for (int i = 0; i < 64; i += 4) {
      float bq[NT][4];
#pragma unroll
      for (int t = 0; t < NT; ++t) {
        float4 v = *(const float4*)&stg[t][i];
        bq[t][0] = v.x; bq[t][1] = v.y; bq[t][2] = v.z; bq[t][3] = v.w;
      }
#pragma unroll
      for (int u = 0; u < 4; ++u) {
        float2 w = *(const float2*)&W1s[(i + u) * 130 + l2];
#pragma unroll
        for (int t = 0; t < NT; ++t) {
          a0[t] = fmaf(bq[t][u], w.x, a0[t]);
          a1[t] = fmaf(bq[t][u], w.y, a1[t]);
        }
      }
    }

    // silu + derivative; stage h1
    float d10[NT], d11[NT];
#pragma unroll
    for (int t = 0; t < NT; ++t) {
      float z  = a0[t];
      float s  = 1.0f / (1.0f + expf(-z));
      float h0 = z * s;
      d10[t]   = s * (1.0f + z * (1.0f - s));
      float zb = a1[t];
      float sb = 1.0f / (1.0f + expf(-zb));
      float h1 = zb * sb;
      d11[t]   = sb * (1.0f + zb * (1.0f - sb));
      float2 hh; hh.x = h0; hh.y = h1;
      *(float2*)&stg[t][l2] = hh;
    }

    // ---- layer2 forward: z2 = W2^T h1 + b2 ----
    float a2[NT];
#pragma unroll
    for (int t = 0; t < NT; ++t) a2[t] = rb2;
    for (int k = 0; k < 128; k += 4) {
      float bh[NT][4];
#pragma unroll
      for (int t = 0; t < NT; ++t) {
        float4 v = *(const float4*)&stg[t][k];
        bh[t][0] = v.x; bh[t][1] = v.y; bh[t][2] = v.z; bh[t][3] = v.w;
      }
      float2 wA = *(const float2*)&W2Ts[lane * 130 + k];
      float2 wB = *(const float2*)&W2Ts[lane * 130 + k + 2];
#pragma unroll
      for (int t = 0; t < NT; ++t) {
        a2[t] = fmaf(bh[t][0], wA.x, a2[t]);
        a2[t] = fmaf(bh[t][1], wA.y, a2[t]);
        a2[t] = fmaf(bh[t][2], wB.x, a2[t]);
        a2[t] = fmaf(bh[t][3], wB.y, a2[t]);
      }
    }

    // g2 = W3 * silu'(z2); stage
#pragma unroll
    for (int t = 0; t < NT; ++t) {
      float z = a2[t];
      float s = 1.0f / (1.0f + expf(-z));
      stg[t][lane] = rw3 * (s * (1.0f + z * (1.0f - s)));
    }

    // ---- backward through W2: gh1[k] = sum_j g2[j] * W2[k][j] ----
    float c0[NT], c1[NT];
#pragma unroll
    for (int t = 0; t < NT; ++t) { c0[t] = 0.0f; c1[t] = 0.0f; }
    for (int j = 0; j < 64; j += 4) {
      float bg[NT][4];
#pragma unroll
      for (int t = 0; t < NT; ++t) {
        float4 v = *(const float4*)&stg[t][j];
        bg[t][0] = v.x; bg[t][1] = v.y; bg[t][2] = v.z; bg[t][3] = v.w;
      }
#pragma unroll
      for (int u = 0; u < 4; ++u) {
        float2 w = *(const float2*)&W2Ts[(j + u) * 130 + l2];
#pragma unroll
        for (int t = 0; t < NT; ++t) {
          c0[t] = fmaf(bg[t][u], w.x, c0[t]);
          c1[t] = fmaf(bg[t][u], w.y, c1[t]);
        }
      }
    }

    // g1 = gh1 * silu'(z1); stage
#pragma unroll
    for (int t = 0; t < NT; ++t) {
      float2 gg; gg.x = c0[t] * d10[t]; gg.y = c1[t] * d11[t];
      *(float2*)&stg[t][l2] = gg;
    }

    // ---- backward through W1: grad[i] = sum_k g1[k] * W1[i][k] ----
#pragma unroll
    for (int t = 0; t < NT; ++t) gr[t] = 0.0f;
    for (int k = 0; k < 128; k += 4) {
      float bg[NT][4];
#pragma unroll
      for (int t = 0; t < NT; ++t) {
        float4 v = *(const float4*)&stg[t][k];
        bg[t][0] = v.x; bg[t][1] = v.y; bg[t][2] = v.z; bg[t][3] = v.w;
      }
      float2 wA = *(const float2*)&W1s[lane * 130 + k];
      float2 wB = *(const float2*)&W1s[lane * 130 + k + 2];
#pragma unroll
      for (int t = 0; t < NT; ++t) {
        gr[t] = fmaf(bg[t][0], wA.x, gr[t]);
        gr[t] = fmaf(bg[t][1], wA.y, gr[t]);
        gr[t] = fmaf(bg[t][2], wB.x, gr[t]);
        gr[t] = fmaf(bg[t][3], wB.y, gr[t]);
      }
    }
  };

  evalgrad(q, g);  // gradV at initial positions

  for (int s = 0; s < STEPS; ++s) {
    // distances BEFORE leapfrog (matches scan order)
#pragma unroll
    for (int pr = 0; pr < 2; ++pr) {
      float xq = q[2 * pr], yq = q[2 * pr + 1];
      float df = xq - yq;
      float d2 = wsum(df * df);
      float x2 = fminf(wsum(xq * xq), 0.999f);
      float y2 = fminf(wsum(yq * yq), 0.999f);
      float arg = 1.0f + 2.0f * d2 / ((1.0f - x2) * (1.0f - y2) + EPSV);
      float d = acoshf(fmaxf(arg, 1.0f + EPSV));
      if (lane == 0) out[s * BATCH + pair0 + pr] = d;
    }

    float qn[NT], ph[NT];
#pragma unroll
    for (int t = 0; t < NT; ++t) {
      ph[t] = (p[t] - 0.5f * DT * g[t]) * (1.0f - DAMP);
      float q2r = wsum(q[t] * q[t]);
      float q2c = fminf(q2r, 0.999f);
      float lam = 2.0f / (1.0f - q2c);
      float v   = DT * ph[t] / (lam * lam);
      // exp_map(q, v)
      float vn  = sqrtf(wsum(v * v)) + EPSV;
      float mag = tanhf(fminf(lam * vn * 0.5f, 15.0f));
      float y   = mag * (v / vn);
      // mobius_add(q, y)  (x2 UNclamped here, per reference)
      float y2  = wsum(y * y);
      float xy  = wsum(q[t] * y);
      float num = (1.0f + 2.0f * xy + y2) * q[t] + (1.0f - q2r) * y;
      float den = 1.0f + 2.0f * xy + q2r * y2;
      float r   = num / (den + EPSV);
      float rn  = sqrtf(wsum(r * r));
      float sc  = (rn > 0.99f) ? (0.99f / (rn + EPSV)) : 1.0f;
      qn[t] = r * sc;
    }

    evalgrad(qn, g);  // gradV(q_new); also next step's gradV(q)
#pragma unroll
    for (int t = 0; t < NT; ++t) {
      p[t] = ph[t] - 0.5f * DT * g[t];
      q[t] = qn[t];
    }
  }
}

}  // namespace

extern "C" void kernel_launch(void* const* d_in, const int* in_sizes, int n_in,
                              void* d_out, int out_size, void* d_ws, size_t ws_size,
                              hipStream_t stream) {
  (void)in_sizes; (void)n_in; (void)out_size; (void)d_ws; (void)ws_size;
  const float* q0 = (const float*)d_in[0];
  const float* pd = (const float*)d_in[1];
  const float* W1 = (const float*)d_in[2];
  const float* b1 = (const float*)d_in[3];
  const float* W2 = (const float*)d_in[4];
  const float* b2 = (const float*)d_in[5];
  const float* W3 = (const float*)d_in[6];
  // d_in[7] = b3: constant offset, does not affect gradV or distances.
  float* out = (float*)d_out;

  geo_scramble_kernel<<<dim3(256), dim3(256), 0, stream>>>(q0, pd, W1, b1, W2, b2, W3, out);
}

// Round 2
// 986.940 us; speedup vs baseline: 1.3939x; 1.3939x over previous
//
#include <hip/hip_runtime.h>
#include <math.h>

namespace {

constexpr int   STEPS = 100;
constexpr int   BATCH = 2048;
constexpr float DT    = 0.05f;
constexpr float DAMP  = 0.01f;
constexpr float EPSV  = 1e-8f;
constexpr int   NT    = 2;   // trajectories per wave (1 pair: base + perturbed)

__device__ __forceinline__ float wsum(float v) {
#pragma unroll
  for (int o = 32; o > 0; o >>= 1) v += __shfl_xor(v, o, 64);
  return v;
}

__global__ __launch_bounds__(256, 2)
void geo_scramble_kernel(const float* __restrict__ q0g, const float* __restrict__ pdg,
                         const float* __restrict__ W1g, const float* __restrict__ b1g,
                         const float* __restrict__ W2g, const float* __restrict__ b2g,
                         const float* __restrict__ W3g, float* __restrict__ out)
{
  // W1s[i][h]  : [64][130]  (stride 130 == 2 mod 32 -> both read orientations conflict-free)
  // W2Ts[j][k] : [64][130]  (W2Ts[j][k] = W2[k][j])
  __shared__ __align__(16) float W1s[64 * 130];
  __shared__ __align__(16) float W2Ts[64 * 130];
  __shared__ __align__(16) float stg_all[4][NT][128];  // per-wave broadcast staging

  const int tid  = threadIdx.x;
  const int lane = tid & 63;
  const int wave = tid >> 6;

  for (int idx = tid; idx < 64 * 128; idx += 256) {
    int r = idx >> 7, c = idx & 127;
    W1s[r * 130 + c] = W1g[idx];
  }
  for (int idx = tid; idx < 64 * 128; idx += 256) {
    int j = idx >> 7, k = idx & 127;
    W2Ts[j * 130 + k] = W2g[k * 64 + j];
  }
  __syncthreads();

  const float rb10 = b1g[2 * lane];
  const float rb11 = b1g[2 * lane + 1];
  const float rb2  = b2g[lane];
  const float rw3  = W3g[lane];

  float (*stg)[128] = stg_all[wave];
  const int pair = blockIdx.x * 4 + wave;  // one pair per wave
  const int l2 = lane << 1;

  float q[NT], p[NT], g[NT];
#pragma unroll
  for (int t = 0; t < NT; ++t) {
    float base = q0g[pair * 64 + lane];
    if (t & 1) {
      float qp = base + 1e-4f * pdg[pair * 64 + lane];
      float n  = sqrtf(wsum(qp * qp));
      float sc = (n > 0.99f) ? (0.99f / (n + EPSV)) : 1.0f;
      q[t] = qp * sc;
    } else {
      q[t] = base;
    }
    p[t] = 0.0f;
  }

  // Batched gradient of V(q) = W3 . silu(W2 . silu(W1 q + b1) + b2) for NT trajectories.
  // Lane j owns latent dim j and hidden dims {2j, 2j+1}.
  auto evalgrad = [&](const float* x, float* gr) {
    // stage input for broadcast
#pragma unroll
    for (int t = 0; t < NT; ++t) stg[t][lane] = x[t];

    // ---- layer1 forward: z1 = W1^T q + b1 ----
    float a0[NT], a1[NT];
#pragma unroll
    for (int t = 0; t < NT; ++t) { a0[t] = rb10; a1[t] = rb11; }
    for (int i = 0; i < 64; i += 4) {
      float bq[NT][4];
#pragma unroll
      for (int t = 0; t < NT; ++t) {
        float4 v = *(const float4*)&stg[t][i];
        bq[t][0] = v.x; bq[t][1] = v.y; bq[t][2] = v.z; bq[t][3] = v.w;
      }
#pragma unroll
      for (int u = 0; u < 4; ++u) {
        float2 w = *(const float2*)&W1s[(i + u) * 130 + l2];
#pragma unroll
        for (int t = 0; t < NT; ++t) {
          a0[t] = fmaf(bq[t][u], w.x, a0[t]);
          a1[t] = fmaf(bq[t][u], w.y, a1[t]);
        }
      }
    }

    // silu + derivative; stage h1
    float d10[NT], d11[NT];
#pragma unroll
    for (int t = 0; t < NT; ++t) {
      float z  = a0[t];
      float s  = 1.0f / (1.0f + expf(-z));
      float h0 = z * s;
      d10[t]   = s * (1.0f + z * (1.0f - s));
      float zb = a1[t];
      float sb = 1.0f / (1.0f + expf(-zb));
      float h1 = zb * sb;
      d11[t]   = sb * (1.0f + zb * (1.0f - sb));
      float2 hh; hh.x = h0; hh.y = h1;
      *(float2*)&stg[t][l2] = hh;
    }

    // ---- layer2 forward: z2 = W2^T h1 + b2 ----
    float a2[NT];
#pragma unroll
    for (int t = 0; t < NT; ++t) a2[t] = rb2;
    for (int k = 0; k < 128; k += 4) {
      float bh[NT][4];
#pragma unroll
      for (int t = 0; t < NT; ++t) {
        float4 v = *(const float4*)&stg[t][k];
        bh[t][0] = v.x; bh[t][1] = v.y; bh[t][2] = v.z; bh[t][3] = v.w;
      }
      float2 wA = *(const float2*)&W2Ts[lane * 130 + k];
      float2 wB = *(const float2*)&W2Ts[lane * 130 + k + 2];
#pragma unroll
      for (int t = 0; t < NT; ++t) {
        a2[t] = fmaf(bh[t][0], wA.x, a2[t]);
        a2[t] = fmaf(bh[t][1], wA.y, a2[t]);
        a2[t] = fmaf(bh[t][2], wB.x, a2[t]);
        a2[t] = fmaf(bh[t][3], wB.y, a2[t]);
      }
    }

    // g2 = W3 * silu'(z2); stage
#pragma unroll
    for (int t = 0; t < NT; ++t) {
      float z = a2[t];
      float s = 1.0f / (1.0f + expf(-z));
      stg[t][lane] = rw3 * (s * (1.0f + z * (1.0f - s)));
    }

    // ---- backward through W2: gh1[k] = sum_j g2[j] * W2[k][j] ----
    float c0[NT], c1[NT];
#pragma unroll
    for (int t = 0; t < NT; ++t) { c0[t] = 0.0f; c1[t] = 0.0f; }
    for (int j = 0; j < 64; j += 4) {
      float bg[NT][4];
#pragma unroll
      for (int t = 0; t < NT; ++t) {
        float4 v = *(const float4*)&stg[t][j];
        bg[t][0] = v.x; bg[t][1] = v.y; bg[t][2] = v.z; bg[t][3] = v.w;
      }
#pragma unroll
      for (int u = 0; u < 4; ++u) {
        float2 w = *(const float2*)&W2Ts[(j + u) * 130 + l2];
#pragma unroll
        for (int t = 0; t < NT; ++t) {
          c0[t] = fmaf(bg[t][u], w.x, c0[t]);
          c1[t] = fmaf(bg[t][u], w.y, c1[t]);
        }
      }
    }

    // g1 = gh1 * silu'(z1); stage
#pragma unroll
    for (int t = 0; t < NT; ++t) {
      float2 gg; gg.x = c0[t] * d10[t]; gg.y = c1[t] * d11[t];
      *(float2*)&stg[t][l2] = gg;
    }

    // ---- backward through W1: grad[i] = sum_k g1[k] * W1[i][k] ----
#pragma unroll
    for (int t = 0; t < NT; ++t) gr[t] = 0.0f;
    for (int k = 0; k < 128; k += 4) {
      float bg[NT][4];
#pragma unroll
      for (int t = 0; t < NT; ++t) {
        float4 v = *(const float4*)&stg[t][k];
        bg[t][0] = v.x; bg[t][1] = v.y; bg[t][2] = v.z; bg[t][3] = v.w;
      }
      float2 wA = *(const float2*)&W1s[lane * 130 + k];
      float2 wB = *(const float2*)&W1s[lane * 130 + k + 2];
#pragma unroll
      for (int t = 0; t < NT; ++t) {
        gr[t] = fmaf(bg[t][0], wA.x, gr[t]);
        gr[t] = fmaf(bg[t][1], wA.y, gr[t]);
        gr[t] = fmaf(bg[t][2], wB.x, gr[t]);
        gr[t] = fmaf(bg[t][3], wB.y, gr[t]);
      }
    }
  };

  evalgrad(q, g);  // gradV at initial positions

  for (int s = 0; s < STEPS; ++s) {
    // distance BEFORE leapfrog (matches scan order)
    {
      float xq = q[0], yq = q[1];
      float df = xq - yq;
      float d2 = wsum(df * df);
      float x2 = fminf(wsum(xq * xq), 0.999f);
      float y2 = fminf(wsum(yq * yq), 0.999f);
      float arg = 1.0f + 2.0f * d2 / ((1.0f - x2) * (1.0f - y2) + EPSV);
      float d = acoshf(fmaxf(arg, 1.0f + EPSV));
      if (lane == 0) out[s * BATCH + pair] = d;
    }

    float qn[NT], ph[NT];
#pragma unroll
    for (int t = 0; t < NT; ++t) {
      ph[t] = (p[t] - 0.5f * DT * g[t]) * (1.0f - DAMP);
      float q2r = wsum(q[t] * q[t]);
      float q2c = fminf(q2r, 0.999f);
      float lam = 2.0f / (1.0f - q2c);
      float v   = DT * ph[t] / (lam * lam);
      // exp_map(q, v)
      float vn  = sqrtf(wsum(v * v)) + EPSV;
      float mag = tanhf(fminf(lam * vn * 0.5f, 15.0f));
      float y   = mag * (v / vn);
      // mobius_add(q, y)  (x2 UNclamped here, per reference)
      float y2  = wsum(y * y);
      float xy  = wsum(q[t] * y);
      float num = (1.0f + 2.0f * xy + y2) * q[t] + (1.0f - q2r) * y;
      float den = 1.0f + 2.0f * xy + q2r * y2;
      float r   = num / (den + EPSV);
      float rn  = sqrtf(wsum(r * r));
      float sc  = (rn > 0.99f) ? (0.99f / (rn + EPSV)) : 1.0f;
      qn[t] = r * sc;
    }

    evalgrad(qn, g);  // gradV(q_new); also next step's gradV(q)
#pragma unroll
    for (int t = 0; t < NT; ++t) {
      p[t] = ph[t] - 0.5f * DT * g[t];
      q[t] = qn[t];
    }
  }
}

}  // namespace

extern "C" void kernel_launch(void* const* d_in, const int* in_sizes, int n_in,
                              void* d_out, int out_size, void* d_ws, size_t ws_size,
                              hipStream_t stream) {
  (void)in_sizes; (void)n_in; (void)out_size; (void)d_ws; (void)ws_size;
  const float* q0 = (const float*)d_in[0];
  const float* pd = (const float*)d_in[1];
  const float* W1 = (const float*)d_in[2];
  const float* b1 = (const float*)d_in[3];
  const float* W2 = (const float*)d_in[4];
  const float* b2 = (const float*)d_in[5];
  const float* W3 = (const float*)d_in[6];
  // d_in[7] = b3: constant offset, does not affect gradV or distances.
  float* out = (float*)d_out;

  geo_scramble_kernel<<<dim3(512), dim3(256), 0, stream>>>(q0, pd, W1, b1, W2, b2, W3, out);
}